// Round 3
// baseline (731.594 us; speedup 1.0000x reference)
//
#include <hip/hip_runtime.h>
#include <cstdint>
#include <cstddef>

typedef __bf16 bf16;
typedef __bf16 bf16x8 __attribute__((ext_vector_type(8)));
typedef float  f32x4  __attribute__((ext_vector_type(4)));

// ---------------------------------------------------------------------------
// elementwise fp32 -> bf16 cast, 4 elems/thread, n % 4 == 0
// ---------------------------------------------------------------------------
__global__ void cast_to_bf16(const float* __restrict__ in, bf16* __restrict__ out, int n)
{
    const int i = (blockIdx.x * 256 + threadIdx.x) * 4;
    if (i < n) {
        const float4 v = *(const float4*)(in + i);
        out[i]     = (bf16)v.x;
        out[i + 1] = (bf16)v.y;
        out[i + 2] = (bf16)v.z;
        out[i + 3] = (bf16)v.w;
    }
}

// ---------------------------------------------------------------------------
// fused transpose + cast: out[c*R + r] = (bf16)in[r*C + c]; in is RxC fp32.
// grid (C/32, R/32), block (32,8).
// ---------------------------------------------------------------------------
__global__ void transpose_cast(const float* __restrict__ in, bf16* __restrict__ out,
                               int R, int Ccols)
{
    __shared__ float tile[32][33];
    const int c0 = blockIdx.x * 32;
    const int r0 = blockIdx.y * 32;
    const int tx = threadIdx.x, ty = threadIdx.y;
    for (int i = ty; i < 32; i += 8)
        tile[i][tx] = in[(size_t)(r0 + i) * Ccols + c0 + tx];
    __syncthreads();
    for (int i = ty; i < 32; i += 8)
        out[(size_t)(c0 + i) * R + r0 + tx] = (bf16)tile[tx][i];
}

// ---------------------------------------------------------------------------
// C[M,N] = A[M,K] @ Bt[N,K]^T + bias[N]; bf16 A/B, fp32 accum.
// Dual epilogue: fp32 C (if non-null) and/or bf16 Cb (if non-null).
// 128x128 tile, BK=64, 4 waves 2x2, 4x4 16x16x32 MFMAs per wave.
// M,N multiples of 128; K multiple of 64.
// ---------------------------------------------------------------------------
__global__ __launch_bounds__(256, 2)
void gemm_bt(const bf16* __restrict__ A, const bf16* __restrict__ Bt,
             const float* __restrict__ bias, float* __restrict__ C,
             bf16* __restrict__ Cb, int M, int N, int K)
{
    __shared__ bf16 As[128 * 64];
    __shared__ bf16 Bs[128 * 64];
    const int tid  = threadIdx.x;
    const int wave = tid >> 6;
    const int lane = tid & 63;
    const int quad = lane >> 4;
    const int l15  = lane & 15;
    const int m0   = blockIdx.y * 128;
    const int n0   = blockIdx.x * 128;
    const int wm   = (wave >> 1) * 64;
    const int wn   = (wave & 1) * 64;

    const int srow = tid >> 3;
    const int scol = (tid & 7) * 8;
    const bf16* Ab = A  + (size_t)(m0 + srow) * K + scol;
    const bf16* Bb = Bt + (size_t)(n0 + srow) * K + scol;

    f32x4 acc[4][4] = {};

    for (int k0 = 0; k0 < K; k0 += 64) {
        bf16x8 ra[4], rb[4];
#pragma unroll
        for (int i = 0; i < 4; ++i) {
            ra[i] = *(const bf16x8*)(Ab + (size_t)(i * 32) * K + k0);
            rb[i] = *(const bf16x8*)(Bb + (size_t)(i * 32) * K + k0);
        }
        __syncthreads();
#pragma unroll
        for (int i = 0; i < 4; ++i) {
            *(bf16x8*)&As[(i * 32 + srow) * 64 + scol] = ra[i];
            *(bf16x8*)&Bs[(i * 32 + srow) * 64 + scol] = rb[i];
        }
        __syncthreads();
#pragma unroll
        for (int ks = 0; ks < 2; ++ks) {
            bf16x8 af[4], bfr[4];
#pragma unroll
            for (int i = 0; i < 4; ++i)
                af[i] = *(const bf16x8*)&As[(wm + i * 16 + l15) * 64 + ks * 32 + quad * 8];
#pragma unroll
            for (int j = 0; j < 4; ++j)
                bfr[j] = *(const bf16x8*)&Bs[(wn + j * 16 + l15) * 64 + ks * 32 + quad * 8];
#pragma unroll
            for (int i = 0; i < 4; ++i)
#pragma unroll
                for (int j = 0; j < 4; ++j)
                    acc[i][j] = __builtin_amdgcn_mfma_f32_16x16x32_bf16(af[i], bfr[j], acc[i][j], 0, 0, 0);
        }
    }

    // C/D layout: col = lane&15, row = quad*4 + r (verified m89/m91)
#pragma unroll
    for (int j = 0; j < 4; ++j) {
        const int col = n0 + wn + j * 16 + l15;
        const float bv = bias[col];
#pragma unroll
        for (int i = 0; i < 4; ++i) {
            const int row = m0 + wm + i * 16 + quad * 4;
#pragma unroll
            for (int r = 0; r < 4; ++r) {
                const float v = acc[i][j][r] + bv;
                if (C)  C [(size_t)(row + r) * N + col] = v;
                if (Cb) Cb[(size_t)(row + r) * N + col] = (bf16)v;
            }
        }
    }
}

// vC (B*S, H*128) bf16 -> vT (B*H, 128, S). grid (S/32, 128/32, 32), block (32,8)
__global__ void transpose_v(const bf16* __restrict__ vC, bf16* __restrict__ vT)
{
    __shared__ bf16 tile[32][33];
    const int bh = blockIdx.z, b = bh >> 4, h = bh & 15;
    const int s0 = blockIdx.x * 32, d0 = blockIdx.y * 32;
    const int tx = threadIdx.x, ty = threadIdx.y;
    for (int i = ty; i < 32; i += 8)
        tile[i][tx] = vC[((size_t)(b * 2048 + s0 + i)) * 2048 + h * 128 + d0 + tx];
    __syncthreads();
    for (int i = ty; i < 32; i += 8)
        vT[((size_t)(bh * 128 + d0 + i)) * 2048 + s0 + tx] = tile[tx][i];
}

// ---------------------------------------------------------------------------
// per-head interleaved RoPE, layout (B*S, H*128); T = float or bf16 input.
// one thread per (b,s,h,pair j<64). inv_freq = 10000^(-j/64).
// ---------------------------------------------------------------------------
#define INVF_C 0.20762050593046014f   // log2(10000)/64

template <typename T>
__global__ void rope_heads(const T* __restrict__ in, bf16* __restrict__ out)
{
    const int idx = blockIdx.x * 256 + threadIdx.x;     // 2*2048*16*64 total
    const int j = idx & 63;
    const int h = (idx >> 6) & 15;
    const int s = (idx >> 10) & 2047;
    const int b = idx >> 21;
    const size_t src = ((size_t)(b * 2048 + s)) * 2048 + h * 128 + 2 * j;
    const float x1 = (float)in[src], x2 = (float)in[src + 1];
    const float ang = (float)s * exp2f(-(float)j * INVF_C);
    float sn, cs;
    sincosf(ang, &sn, &cs);
    out[src]     = (bf16)(x1 * cs - x2 * sn);
    out[src + 1] = (bf16)(x1 * sn + x2 * cs);
}

// ---------------------------------------------------------------------------
// Flash attention, causal. Split operands, all bf16:
//   qC,qR,kC,kR : (B*S, H*128) row-major;  Vt : (B*H, 128, S).
// Per block: one (b,h), 64 q-rows (16 per wave -> wave-local softmax), BKV=64.
// score(q,k) = qC.kC + qR.kR over d=128+128; scale 1/sqrt(256).
// ctx written (B*S, H*128) bf16 for the final GEMM.
// LDS: Ks 64x264 + Vs 128x72 + Ps 64x72 = 61440 B.
// ---------------------------------------------------------------------------
__global__ __launch_bounds__(256, 2)
void mla_attn(const bf16* __restrict__ qCp, const bf16* __restrict__ qRp,
              const bf16* __restrict__ kCp, const bf16* __restrict__ kRp,
              const bf16* __restrict__ Vt, bf16* __restrict__ ctx)
{
    __shared__ bf16 Ks[64 * 264];
    __shared__ bf16 Vs[128 * 72];
    __shared__ bf16 Ps[64 * 72];
    const int bh   = blockIdx.y;
    const int b    = bh >> 4, hh = bh & 15;
    const int q0   = blockIdx.x * 64;
    const int tid  = threadIdx.x;
    const int wave = tid >> 6;
    const int lane = tid & 63;
    const int quad = lane >> 4;
    const int l15  = lane & 15;

    // Q fragments resident (A-operand: m=lane&15, k=quad*8+j).
    bf16x8 qf[8];
    {
        const size_t qoff = ((size_t)(b * 2048 + q0 + wave * 16 + l15)) * 2048
                          + hh * 128 + quad * 8;
#pragma unroll
        for (int ks = 0; ks < 4; ++ks) {
            qf[ks]     = *(const bf16x8*)(qCp + qoff + ks * 32);
            qf[4 + ks] = *(const bf16x8*)(qRp + qoff + ks * 32);
        }
    }

    float mstate[4], lstate[4];
    f32x4 o[8];
#pragma unroll
    for (int r = 0; r < 4; ++r) { mstate[r] = -1e30f; lstate[r] = 0.0f; }
#pragma unroll
    for (int dt = 0; dt < 8; ++dt) { f32x4 z = {0.f, 0.f, 0.f, 0.f}; o[dt] = z; }

    const int krow = tid >> 4, kcol = (tid & 15) * 8;
    const int vsr  = tid >> 3, vsc  = (tid & 7) * 8;

    const int ntiles = q0 / 64 + 1;
    for (int t = 0; t < ntiles; ++t) {
        const int kk0 = t * 64;
        __syncthreads();
#pragma unroll
        for (int it = 0; it < 4; ++it) {   // Ks: 64 rows x (128 | 128)
            const int row = it * 16 + krow;
            const size_t g = ((size_t)(b * 2048 + kk0 + row)) * 2048 + hh * 128 + kcol;
            *(bf16x8*)&Ks[row * 264 + kcol]       = *(const bf16x8*)(kCp + g);
            *(bf16x8*)&Ks[row * 264 + 128 + kcol] = *(const bf16x8*)(kRp + g);
        }
#pragma unroll
        for (int it = 0; it < 4; ++it) {   // Vs: 128 d-rows x 64 kk
            const int d = it * 32 + vsr;
            *(bf16x8*)&Vs[d * 72 + vsc] =
                *(const bf16x8*)(Vt + ((size_t)(bh * 128 + d)) * 2048 + kk0 + vsc);
        }
        __syncthreads();

        f32x4 sc[4] = {};
#pragma unroll
        for (int ks = 0; ks < 8; ++ks)
#pragma unroll
            for (int j = 0; j < 4; ++j) {
                bf16x8 kf = *(const bf16x8*)&Ks[(j * 16 + l15) * 264 + ks * 32 + quad * 8];
                sc[j] = __builtin_amdgcn_mfma_f32_16x16x32_bf16(qf[ks], kf, sc[j], 0, 0, 0);
            }

        const bool diag = (t == ntiles - 1);
        float rowmax[4] = {-1e30f, -1e30f, -1e30f, -1e30f};
#pragma unroll
        for (int j = 0; j < 4; ++j) {
            const int kkcol = kk0 + j * 16 + l15;
#pragma unroll
            for (int r = 0; r < 4; ++r) {
                float s = sc[j][r] * 0.0625f;                 // 1/sqrt(256)
                if (diag && (kkcol > q0 + wave * 16 + quad * 4 + r)) s = -1e30f;
                sc[j][r] = s;
                rowmax[r] = fmaxf(rowmax[r], s);
            }
        }
#pragma unroll
        for (int r = 0; r < 4; ++r) {
            float v = rowmax[r];
            v = fmaxf(v, __shfl_xor(v, 1, 64));
            v = fmaxf(v, __shfl_xor(v, 2, 64));
            v = fmaxf(v, __shfl_xor(v, 4, 64));
            v = fmaxf(v, __shfl_xor(v, 8, 64));
            rowmax[r] = v;
        }
        float alpha[4];
#pragma unroll
        for (int r = 0; r < 4; ++r) {
            const float mnew = fmaxf(mstate[r], rowmax[r]);
            alpha[r] = __expf(mstate[r] - mnew);
            mstate[r] = mnew;
        }
        float rowsum[4] = {0.f, 0.f, 0.f, 0.f};
#pragma unroll
        for (int j = 0; j < 4; ++j)
#pragma unroll
            for (int r = 0; r < 4; ++r) {
                const float p = __expf(sc[j][r] - mstate[r]);
                sc[j][r] = p;
                rowsum[r] += p;
            }
#pragma unroll
        for (int r = 0; r < 4; ++r) {
            float v = rowsum[r];
            v += __shfl_xor(v, 1, 64);
            v += __shfl_xor(v, 2, 64);
            v += __shfl_xor(v, 4, 64);
            v += __shfl_xor(v, 8, 64);
            lstate[r] = lstate[r] * alpha[r] + v;
        }
        // P: C-layout -> LDS -> A-operand layout (verified transform, m120)
#pragma unroll
        for (int j = 0; j < 4; ++j)
#pragma unroll
            for (int r = 0; r < 4; ++r)
                Ps[(wave * 16 + quad * 4 + r) * 72 + j * 16 + l15] = (bf16)sc[j][r];
#pragma unroll
        for (int dt = 0; dt < 8; ++dt)
#pragma unroll
            for (int r = 0; r < 4; ++r)
                o[dt][r] *= alpha[r];
#pragma unroll
        for (int ks2 = 0; ks2 < 2; ++ks2) {
            bf16x8 pf = *(const bf16x8*)&Ps[(wave * 16 + l15) * 72 + ks2 * 32 + quad * 8];
#pragma unroll
            for (int dt = 0; dt < 8; ++dt) {
                bf16x8 vf = *(const bf16x8*)&Vs[(dt * 16 + l15) * 72 + ks2 * 32 + quad * 8];
                o[dt] = __builtin_amdgcn_mfma_f32_16x16x32_bf16(pf, vf, o[dt], 0, 0, 0);
            }
        }
    }

    float inv_l[4];
#pragma unroll
    for (int r = 0; r < 4; ++r) inv_l[r] = 1.0f / lstate[r];
#pragma unroll
    for (int dt = 0; dt < 8; ++dt) {
        const int d = dt * 16 + l15;
#pragma unroll
        for (int r = 0; r < 4; ++r) {
            const int q = q0 + wave * 16 + quad * 4 + r;
            ctx[((size_t)(b * 2048 + q)) * 2048 + hh * 128 + d] = (bf16)(o[dt][r] * inv_l[r]);
        }
    }
}

// ---------------------------------------------------------------------------
extern "C" void kernel_launch(void* const* d_in, const int* in_sizes, int n_in,
                              void* d_out, int out_size, void* d_ws, size_t ws_size,
                              hipStream_t stream)
{
    // inputs are fp32 per the reference (setup_inputs uses float32 throughout)
    const float* h     = (const float*)d_in[0];
    const float* W_DKV = (const float*)d_in[1];
    const float* b_DKV = (const float*)d_in[2];
    const float* W_UK  = (const float*)d_in[3];
    const float* b_UK  = (const float*)d_in[4];
    const float* W_UV  = (const float*)d_in[5];
    const float* b_UV  = (const float*)d_in[6];
    const float* W_DQ  = (const float*)d_in[7];
    const float* b_DQ  = (const float*)d_in[8];
    const float* W_UQ  = (const float*)d_in[9];
    const float* b_UQ  = (const float*)d_in[10];
    const float* W_KR  = (const float*)d_in[11];
    const float* b_KR  = (const float*)d_in[12];
    const float* W_O   = (const float*)d_in[13];
    const float* b_O   = (const float*)d_in[14];

    float* out   = (float*)d_out;             // (4096, 2048)  output 0, fp32
    float* cKV_f = out + (size_t)8388608;     // (4096, 512)   output 1
    float* krc_f = out + (size_t)10485760;    // (4096, 2048)  output 2

    // out-proper (33.5 MB fp32) is dead until the final GEMM -> stash bf16
    // vT (16.8 MB) + qR (16.8 MB) there.
    bf16* vT = (bf16*)d_out;                  // 32x128x2048
    bf16* qR = (bf16*)d_out + 8388608;        // (B*S, H*128)

    // ws (bf16 elements), total 46,137,344 el = 92.3 MB:
    bf16* ws   = (bf16*)d_ws;
    bf16* hb   = ws + 0;           // 8.4M  h in bf16; reused as kR after cQ
    bf16* Wt   = ws + 8388608;     // 4.2M  one transposed weight at a time
    bf16* cKVb = ws + 12582912;    // 2.1M
    bf16* kC   = ws + 14680064;    // 8.4M
    bf16* vC   = ws + 23068672;    // 8.4M  -> ctx after transpose_v
    bf16* cQ   = ws + 31457280;    // 6.3M
    bf16* qC   = ws + 37748736;    // 8.4M
    bf16* kR   = hb;               // hb dead after the cQ GEMM
    bf16* ctx  = vC;               // vC dead after transpose_v

    dim3 tb(32, 8);

    cast_to_bf16<<<8192, 256, 0, stream>>>(h, hb, 8388608);

    transpose_cast<<<dim3(16, 64), tb, 0, stream>>>(W_DKV, Wt, 2048, 512);
    gemm_bt<<<dim3(4, 32),  256, 0, stream>>>(hb, Wt, b_DKV, cKV_f, cKVb, 4096, 512,  2048);

    transpose_cast<<<dim3(64, 64), tb, 0, stream>>>(W_KR, Wt, 2048, 2048);
    gemm_bt<<<dim3(16, 32), 256, 0, stream>>>(hb, Wt, b_KR, krc_f, nullptr, 4096, 2048, 2048);

    transpose_cast<<<dim3(48, 64), tb, 0, stream>>>(W_DQ, Wt, 2048, 1536);
    gemm_bt<<<dim3(12, 32), 256, 0, stream>>>(hb, Wt, b_DQ, nullptr, cQ, 4096, 1536, 2048);
    // hb dead from here

    transpose_cast<<<dim3(64, 16), tb, 0, stream>>>(W_UK, Wt, 512, 2048);
    gemm_bt<<<dim3(16, 32), 256, 0, stream>>>(cKVb, Wt, b_UK, nullptr, kC, 4096, 2048, 512);

    transpose_cast<<<dim3(64, 16), tb, 0, stream>>>(W_UV, Wt, 512, 2048);
    gemm_bt<<<dim3(16, 32), 256, 0, stream>>>(cKVb, Wt, b_UV, nullptr, vC, 4096, 2048, 512);

    transpose_cast<<<dim3(64, 48), tb, 0, stream>>>(W_UQ, Wt, 1536, 2048);
    gemm_bt<<<dim3(16, 32), 256, 0, stream>>>(cQ, Wt, b_UQ, nullptr, qC, 4096, 2048, 1536);

    rope_heads<float><<<16384, 256, 0, stream>>>(krc_f, kR);
    rope_heads<bf16 ><<<16384, 256, 0, stream>>>(qC, qR);
    transpose_v<<<dim3(64, 4, 32), tb, 0, stream>>>(vC, vT);   // vC consumed

    mla_attn<<<dim3(32, 32), 256, 0, stream>>>(qC, qR, kC, kR, vT, ctx);

    transpose_cast<<<dim3(64, 64), tb, 0, stream>>>(W_O, Wt, 2048, 2048);
    gemm_bt<<<dim3(16, 32), 256, 0, stream>>>(ctx, Wt, b_O, out, nullptr, 4096, 2048, 2048);
}

// Round 4
// 640.642 us; speedup vs baseline: 1.1420x; 1.1420x over previous
//
#include <hip/hip_runtime.h>
#include <cstdint>
#include <cstddef>

typedef __bf16 bf16;
typedef __bf16 bf16x8 __attribute__((ext_vector_type(8)));
typedef float  f32x4  __attribute__((ext_vector_type(4)));

// global -> LDS async copy, 16B per lane. LDS base must be wave-uniform;
// HW scatters lane i at base + 16*i. (m97-verified pattern.)
__device__ __forceinline__ void async_copy16(const void* g, void* l)
{
    auto gp = (__attribute__((address_space(1))) const void*)(reinterpret_cast<uintptr_t>(g));
    auto lp = (__attribute__((address_space(3))) void*)(uint32_t)(reinterpret_cast<uintptr_t>(l));
    __builtin_amdgcn_global_load_lds(gp, lp, 16, 0, 0);
}

// ---------------------------------------------------------------------------
// elementwise fp32 -> bf16 cast, 4 elems/thread, n % 4 == 0
// ---------------------------------------------------------------------------
__global__ void cast_to_bf16(const float* __restrict__ in, bf16* __restrict__ out, int n)
{
    const int i = (blockIdx.x * 256 + threadIdx.x) * 4;
    if (i < n) {
        const float4 v = *(const float4*)(in + i);
        out[i]     = (bf16)v.x;
        out[i + 1] = (bf16)v.y;
        out[i + 2] = (bf16)v.z;
        out[i + 3] = (bf16)v.w;
    }
}

// ---------------------------------------------------------------------------
// fused transpose + cast: out[c*R + r] = (bf16)in[r*C + c]; in is RxC fp32.
// grid (C/32, R/32), block (32,8).
// ---------------------------------------------------------------------------
__global__ void transpose_cast(const float* __restrict__ in, bf16* __restrict__ out,
                               int R, int Ccols)
{
    __shared__ float tile[32][33];
    const int c0 = blockIdx.x * 32;
    const int r0 = blockIdx.y * 32;
    const int tx = threadIdx.x, ty = threadIdx.y;
    for (int i = ty; i < 32; i += 8)
        tile[i][tx] = in[(size_t)(r0 + i) * Ccols + c0 + tx];
    __syncthreads();
    for (int i = ty; i < 32; i += 8)
        out[(size_t)(c0 + i) * R + r0 + tx] = (bf16)tile[tx][i];
}

// ---------------------------------------------------------------------------
// C[M,N] = A[M,K] @ Bt[N,K]^T + bias[N]; bf16 A/B, fp32 accum.
// Dual epilogue: fp32 C (if non-null) and/or bf16 Cb (if non-null).
// m97 structure: 128x128 tile, BK=64, 4 waves 2x2, global_load_lds width-16
// staging into unpadded LDS. M,N multiples of 128; K multiple of 64.
// ---------------------------------------------------------------------------
__global__ __launch_bounds__(256, 2)
void gemm_bt(const bf16* __restrict__ A, const bf16* __restrict__ Bt,
             const float* __restrict__ bias, float* __restrict__ C,
             bf16* __restrict__ Cb, int M, int N, int K)
{
    __shared__ bf16 As[128 * 64];
    __shared__ bf16 Bs[128 * 64];
    const int tid  = threadIdx.x;
    const int wave = tid >> 6;
    const int lane = tid & 63;
    const int quad = lane >> 4;
    const int l15  = lane & 15;
    const int m0   = blockIdx.y * 128;
    const int n0   = blockIdx.x * 128;
    const int wm   = (wave >> 1) * 64;
    const int wn   = (wave & 1) * 64;

    // staging: wave w covers rows [w*32, w*32+32) in 4 issues of 8 rows;
    // lane l -> row l>>3, col chunk (l&7)*8 (matches lane*16B LDS scatter)
    const int srow = lane >> 3;
    const int scol = (lane & 7) * 8;
    const bf16* Ab = A  + (size_t)(m0 + wave * 32 + srow) * K + scol;
    const bf16* Bb = Bt + (size_t)(n0 + wave * 32 + srow) * K + scol;
    bf16* AsW = &As[(wave * 32) * 64];
    bf16* BsW = &Bs[(wave * 32) * 64];

    f32x4 acc[4][4] = {};

    for (int k0 = 0; k0 < K; k0 += 64) {
        __syncthreads();   // previous tile fully consumed
#pragma unroll
        for (int i = 0; i < 4; ++i) {
            async_copy16(Ab + (size_t)(i * 8) * K + k0, AsW + i * 8 * 64);
            async_copy16(Bb + (size_t)(i * 8) * K + k0, BsW + i * 8 * 64);
        }
        __syncthreads();   // drains vmcnt(0) -> staged data visible
#pragma unroll
        for (int ks = 0; ks < 2; ++ks) {
            bf16x8 af[4], bfr[4];
#pragma unroll
            for (int i = 0; i < 4; ++i)
                af[i] = *(const bf16x8*)&As[(wm + i * 16 + l15) * 64 + ks * 32 + quad * 8];
#pragma unroll
            for (int j = 0; j < 4; ++j)
                bfr[j] = *(const bf16x8*)&Bs[(wn + j * 16 + l15) * 64 + ks * 32 + quad * 8];
#pragma unroll
            for (int i = 0; i < 4; ++i)
#pragma unroll
                for (int j = 0; j < 4; ++j)
                    acc[i][j] = __builtin_amdgcn_mfma_f32_16x16x32_bf16(af[i], bfr[j], acc[i][j], 0, 0, 0);
        }
    }

    // C/D layout: col = lane&15, row = quad*4 + r (verified m89/m91)
#pragma unroll
    for (int j = 0; j < 4; ++j) {
        const int col = n0 + wn + j * 16 + l15;
        const float bv = bias[col];
#pragma unroll
        for (int i = 0; i < 4; ++i) {
            const int row = m0 + wm + i * 16 + quad * 4;
#pragma unroll
            for (int r = 0; r < 4; ++r) {
                const float v = acc[i][j][r] + bv;
                if (C)  C [(size_t)(row + r) * N + col] = v;
                if (Cb) Cb[(size_t)(row + r) * N + col] = (bf16)v;
            }
        }
    }
}

// vC (B*S, H*128) bf16 -> vT (B*H, 128, S). grid (S/32, 128/32, 32), block (32,8)
__global__ void transpose_v(const bf16* __restrict__ vC, bf16* __restrict__ vT)
{
    __shared__ bf16 tile[32][33];
    const int bh = blockIdx.z, b = bh >> 4, h = bh & 15;
    const int s0 = blockIdx.x * 32, d0 = blockIdx.y * 32;
    const int tx = threadIdx.x, ty = threadIdx.y;
    for (int i = ty; i < 32; i += 8)
        tile[i][tx] = vC[((size_t)(b * 2048 + s0 + i)) * 2048 + h * 128 + d0 + tx];
    __syncthreads();
    for (int i = ty; i < 32; i += 8)
        vT[((size_t)(bh * 128 + d0 + i)) * 2048 + s0 + tx] = tile[tx][i];
}

// ---------------------------------------------------------------------------
// per-head interleaved RoPE, layout (B*S, H*128); T = float or bf16 input.
// ---------------------------------------------------------------------------
#define INVF_C 0.20762050593046014f   // log2(10000)/64

template <typename T>
__global__ void rope_heads(const T* __restrict__ in, bf16* __restrict__ out)
{
    const int idx = blockIdx.x * 256 + threadIdx.x;     // 2*2048*16*64 total
    const int j = idx & 63;
    const int h = (idx >> 6) & 15;
    const int s = (idx >> 10) & 2047;
    const int b = idx >> 21;
    const size_t src = ((size_t)(b * 2048 + s)) * 2048 + h * 128 + 2 * j;
    const float x1 = (float)in[src], x2 = (float)in[src + 1];
    const float ang = (float)s * exp2f(-(float)j * INVF_C);
    float sn, cs;
    sincosf(ang, &sn, &cs);
    out[src]     = (bf16)(x1 * cs - x2 * sn);
    out[src + 1] = (bf16)(x1 * sn + x2 * cs);
}

// ---------------------------------------------------------------------------
// Flash attention, causal. Split operands, all bf16:
//   qC,qR,kC,kR : (B*S, H*128) row-major;  Vt : (B*H, 128, S).
// BQ=128 (8 waves x 16 q-rows, wave-local softmax), BKV=64.
// Grid (bh=32, qtile=16): 512 blocks, 2/CU -> all co-resident; bh-major
// linear ids put all q-blocks of one head on one XCD residue (L2 reuse).
// LDS: Ks 64x264 + Vs 128x72 + Ps 128x72 = 70656 B.
// ---------------------------------------------------------------------------
__global__ __launch_bounds__(512, 4)
void mla_attn(const bf16* __restrict__ qCp, const bf16* __restrict__ qRp,
              const bf16* __restrict__ kCp, const bf16* __restrict__ kRp,
              const bf16* __restrict__ Vt, bf16* __restrict__ ctx)
{
    __shared__ bf16 Ks[64 * 264];
    __shared__ bf16 Vs[128 * 72];
    __shared__ bf16 Ps[128 * 72];
    const int bh   = blockIdx.x;
    const int b    = bh >> 4, hh = bh & 15;
    const int q0   = blockIdx.y * 128;
    const int tid  = threadIdx.x;
    const int wave = tid >> 6;
    const int lane = tid & 63;
    const int quad = lane >> 4;
    const int l15  = lane & 15;
    const int wq   = q0 + wave * 16;       // wave's first q row

    // Q fragments resident (A-operand: m=lane&15, k=quad*8+j).
    bf16x8 qf[8];
    {
        const size_t qoff = ((size_t)(b * 2048 + wq + l15)) * 2048
                          + hh * 128 + quad * 8;
#pragma unroll
        for (int ks = 0; ks < 4; ++ks) {
            qf[ks]     = *(const bf16x8*)(qCp + qoff + ks * 32);
            qf[4 + ks] = *(const bf16x8*)(qRp + qoff + ks * 32);
        }
    }

    float mstate[4], lstate[4];
    f32x4 o[8];
#pragma unroll
    for (int r = 0; r < 4; ++r) { mstate[r] = -1e30f; lstate[r] = 0.0f; }
#pragma unroll
    for (int dt = 0; dt < 8; ++dt) { f32x4 z = {0.f, 0.f, 0.f, 0.f}; o[dt] = z; }

    const int krow = tid >> 4, kcol = (tid & 15) * 8;   // K staging (512 thr)
    const int vsr  = tid >> 3, vsc  = (tid & 7) * 8;    // V staging

    const int ntiles = 2 * blockIdx.y + 2;
    for (int t = 0; t < ntiles; ++t) {
        const int kk0 = t * 64;
        __syncthreads();
#pragma unroll
        for (int it = 0; it < 2; ++it) {   // Ks: 64 rows x (128 | 128)
            const int row = it * 32 + krow;
            const size_t g = ((size_t)(b * 2048 + kk0 + row)) * 2048 + hh * 128 + kcol;
            *(bf16x8*)&Ks[row * 264 + kcol]       = *(const bf16x8*)(kCp + g);
            *(bf16x8*)&Ks[row * 264 + 128 + kcol] = *(const bf16x8*)(kRp + g);
        }
#pragma unroll
        for (int it = 0; it < 2; ++it) {   // Vs: 128 d-rows x 64 kk
            const int d = it * 64 + vsr;
            *(bf16x8*)&Vs[d * 72 + vsc] =
                *(const bf16x8*)(Vt + ((size_t)(bh * 128 + d)) * 2048 + kk0 + vsc);
        }
        __syncthreads();

        if (kk0 <= wq + 15) {   // wave-uniform: tile not fully masked
            f32x4 sc[4] = {};
#pragma unroll
            for (int ks = 0; ks < 8; ++ks)
#pragma unroll
                for (int j = 0; j < 4; ++j) {
                    bf16x8 kf = *(const bf16x8*)&Ks[(j * 16 + l15) * 264 + ks * 32 + quad * 8];
                    sc[j] = __builtin_amdgcn_mfma_f32_16x16x32_bf16(qf[ks], kf, sc[j], 0, 0, 0);
                }

            const bool diag = (kk0 + 63 > wq);
            float rowmax[4] = {-1e30f, -1e30f, -1e30f, -1e30f};
#pragma unroll
            for (int j = 0; j < 4; ++j) {
                const int kkcol = kk0 + j * 16 + l15;
#pragma unroll
                for (int r = 0; r < 4; ++r) {
                    float s = sc[j][r] * 0.0625f;             // 1/sqrt(256)
                    if (diag && (kkcol > wq + quad * 4 + r)) s = -1e30f;
                    sc[j][r] = s;
                    rowmax[r] = fmaxf(rowmax[r], s);
                }
            }
#pragma unroll
            for (int r = 0; r < 4; ++r) {  // reduce across the 16 col-lanes
                float v = rowmax[r];
                v = fmaxf(v, __shfl_xor(v, 1, 64));
                v = fmaxf(v, __shfl_xor(v, 2, 64));
                v = fmaxf(v, __shfl_xor(v, 4, 64));
                v = fmaxf(v, __shfl_xor(v, 8, 64));
                rowmax[r] = v;
            }
            float alpha[4];
#pragma unroll
            for (int r = 0; r < 4; ++r) {
                const float mnew = fmaxf(mstate[r], rowmax[r]);
                alpha[r] = __expf(mstate[r] - mnew);
                mstate[r] = mnew;
            }
            float rowsum[4] = {0.f, 0.f, 0.f, 0.f};
#pragma unroll
            for (int j = 0; j < 4; ++j)
#pragma unroll
                for (int r = 0; r < 4; ++r) {
                    const float p = __expf(sc[j][r] - mstate[r]);
                    sc[j][r] = p;
                    rowsum[r] += p;
                }
#pragma unroll
            for (int r = 0; r < 4; ++r) {
                float v = rowsum[r];
                v += __shfl_xor(v, 1, 64);
                v += __shfl_xor(v, 2, 64);
                v += __shfl_xor(v, 4, 64);
                v += __shfl_xor(v, 8, 64);
                lstate[r] = lstate[r] * alpha[r] + v;
            }
            // P: C-layout -> LDS -> A-operand layout (verified, m120)
#pragma unroll
            for (int j = 0; j < 4; ++j)
#pragma unroll
                for (int r = 0; r < 4; ++r)
                    Ps[(wave * 16 + quad * 4 + r) * 72 + j * 16 + l15] = (bf16)sc[j][r];
#pragma unroll
            for (int dt = 0; dt < 8; ++dt)
#pragma unroll
                for (int r = 0; r < 4; ++r)
                    o[dt][r] *= alpha[r];
#pragma unroll
            for (int ks2 = 0; ks2 < 2; ++ks2) {
                bf16x8 pf = *(const bf16x8*)&Ps[(wave * 16 + l15) * 72 + ks2 * 32 + quad * 8];
#pragma unroll
                for (int dt = 0; dt < 8; ++dt) {
                    bf16x8 vf = *(const bf16x8*)&Vs[(dt * 16 + l15) * 72 + ks2 * 32 + quad * 8];
                    o[dt] = __builtin_amdgcn_mfma_f32_16x16x32_bf16(pf, vf, o[dt], 0, 0, 0);
                }
            }
        }
    }

    float inv_l[4];
#pragma unroll
    for (int r = 0; r < 4; ++r) inv_l[r] = 1.0f / lstate[r];
#pragma unroll
    for (int dt = 0; dt < 8; ++dt) {
        const int d = dt * 16 + l15;
#pragma unroll
        for (int r = 0; r < 4; ++r) {
            const int q = wq + quad * 4 + r;
            ctx[((size_t)(b * 2048 + q)) * 2048 + hh * 128 + d] = (bf16)(o[dt][r] * inv_l[r]);
        }
    }
}

// ---------------------------------------------------------------------------
extern "C" void kernel_launch(void* const* d_in, const int* in_sizes, int n_in,
                              void* d_out, int out_size, void* d_ws, size_t ws_size,
                              hipStream_t stream)
{
    const float* h     = (const float*)d_in[0];
    const float* W_DKV = (const float*)d_in[1];
    const float* b_DKV = (const float*)d_in[2];
    const float* W_UK  = (const float*)d_in[3];
    const float* b_UK  = (const float*)d_in[4];
    const float* W_UV  = (const float*)d_in[5];
    const float* b_UV  = (const float*)d_in[6];
    const float* W_DQ  = (const float*)d_in[7];
    const float* b_DQ  = (const float*)d_in[8];
    const float* W_UQ  = (const float*)d_in[9];
    const float* b_UQ  = (const float*)d_in[10];
    const float* W_KR  = (const float*)d_in[11];
    const float* b_KR  = (const float*)d_in[12];
    const float* W_O   = (const float*)d_in[13];
    const float* b_O   = (const float*)d_in[14];

    float* out   = (float*)d_out;             // (4096, 2048)  output 0, fp32
    float* cKV_f = out + (size_t)8388608;     // (4096, 512)   output 1
    float* krc_f = out + (size_t)10485760;    // (4096, 2048)  output 2

    // out-proper (33.5 MB fp32) is dead until the final GEMM -> stash bf16
    // vT (16.8 MB) + qR (16.8 MB) there; both consumed before the final GEMM.
    bf16* vT = (bf16*)d_out;                  // 32x128x2048
    bf16* qR = (bf16*)d_out + 8388608;        // (B*S, H*128)

    // ws (bf16 elements), total 46,137,344 el = 92.3 MB:
    bf16* ws   = (bf16*)d_ws;
    bf16* hb   = ws + 0;           // 8.4M  h in bf16; reused as kR after cQ
    bf16* Wt   = ws + 8388608;     // 4.2M  one transposed weight at a time
    bf16* cKVb = ws + 12582912;    // 2.1M
    bf16* kC   = ws + 14680064;    // 8.4M
    bf16* vC   = ws + 23068672;    // 8.4M  -> ctx after transpose_v
    bf16* cQ   = ws + 31457280;    // 6.3M
    bf16* qC   = ws + 37748736;    // 8.4M
    bf16* kR   = hb;               // hb dead after the cQ GEMM
    bf16* ctx  = vC;               // vC dead after transpose_v

    dim3 tb(32, 8);

    cast_to_bf16<<<8192, 256, 0, stream>>>(h, hb, 8388608);

    transpose_cast<<<dim3(16, 64), tb, 0, stream>>>(W_DKV, Wt, 2048, 512);
    gemm_bt<<<dim3(4, 32),  256, 0, stream>>>(hb, Wt, b_DKV, cKV_f, cKVb, 4096, 512,  2048);

    transpose_cast<<<dim3(64, 64), tb, 0, stream>>>(W_KR, Wt, 2048, 2048);
    gemm_bt<<<dim3(16, 32), 256, 0, stream>>>(hb, Wt, b_KR, krc_f, nullptr, 4096, 2048, 2048);

    transpose_cast<<<dim3(48, 64), tb, 0, stream>>>(W_DQ, Wt, 2048, 1536);
    gemm_bt<<<dim3(12, 32), 256, 0, stream>>>(hb, Wt, b_DQ, nullptr, cQ, 4096, 1536, 2048);
    // hb dead from here

    transpose_cast<<<dim3(64, 16), tb, 0, stream>>>(W_UK, Wt, 512, 2048);
    gemm_bt<<<dim3(16, 32), 256, 0, stream>>>(cKVb, Wt, b_UK, nullptr, kC, 4096, 2048, 512);

    transpose_cast<<<dim3(64, 16), tb, 0, stream>>>(W_UV, Wt, 512, 2048);
    gemm_bt<<<dim3(16, 32), 256, 0, stream>>>(cKVb, Wt, b_UV, nullptr, vC, 4096, 2048, 512);

    transpose_cast<<<dim3(64, 48), tb, 0, stream>>>(W_UQ, Wt, 1536, 2048);
    gemm_bt<<<dim3(16, 32), 256, 0, stream>>>(cQ, Wt, b_UQ, nullptr, qC, 4096, 2048, 1536);

    rope_heads<float><<<16384, 256, 0, stream>>>(krc_f, kR);
    rope_heads<bf16 ><<<16384, 256, 0, stream>>>(qC, qR);
    transpose_v<<<dim3(64, 4, 32), tb, 0, stream>>>(vC, vT);   // vC consumed

    mla_attn<<<dim3(32, 16), 512, 0, stream>>>(qC, qR, kC, kR, vT, ctx);

    transpose_cast<<<dim3(64, 64), tb, 0, stream>>>(W_O, Wt, 2048, 2048);
    gemm_bt<<<dim3(16, 32), 256, 0, stream>>>(ctx, Wt, b_O, out, nullptr, 4096, 2048, 2048);
}